// Round 1
// baseline (5965.263 us; speedup 1.0000x reference)
//
#include <hip/hip_runtime.h>

#define H 128
#define NODE_DIM 64
#define EDGE_DIM 32
#define KPRE (2*H + EDGE_DIM)   // 288
#define KPOST (13*H)            // 1664
#define T_OUT 256
#define L_DEPTH 5
#define EPB 16                  // edges per block (pretrans)
#define NPB 8                   // nodes per block (posttrans)

// ---------------- input MLP: h = relu(node_feat @ W_in + b_in) ----------------
__global__ void k_input_mlp(const float* __restrict__ nf, const float* __restrict__ W,
                            const float* __restrict__ b, float* __restrict__ h, int N) {
    int gid = blockIdx.x * blockDim.x + threadIdx.x;
    int n = gid >> 7, c = gid & 127;
    if (n >= N) return;
    const float* nrow = nf + (size_t)n * NODE_DIM;
    float acc = 0.f;
#pragma unroll 8
    for (int k = 0; k < NODE_DIM; ++k)
        acc += nrow[k] * W[k * H + c];
    acc += b[c];
    h[(size_t)n * H + c] = fmaxf(acc, 0.f);
}

// ---------------- degree + scalers ----------------
__global__ void k_degree(const int* __restrict__ dst, float* __restrict__ deg, int E) {
    int e = blockIdx.x * blockDim.x + threadIdx.x;
    if (e < E) atomicAdd(&deg[dst[e]], 1.0f);
}

__global__ void k_scalers(const float* __restrict__ deg, float* __restrict__ invd,
                          float* __restrict__ amp, float* __restrict__ att, int N) {
    int n = blockIdx.x * blockDim.x + threadIdx.x;
    if (n >= N) return;
    float d = deg[n];
    invd[n] = (d > 0.f) ? (1.f / d) : 0.f;          // 1/max(d,1) == 1/d for d>=1
    float ld = logf(d + 1.f);
    amp[n] = ld;                                     // DELTA == 1.0
    att[n] = (d > 0.f) ? (1.f / ld) : 1.f;
}

// ---------------- fused pretrans GEMM + scatter (sum/max/min) ----------------
__global__ __launch_bounds__(256) void k_pretrans(
    const float* __restrict__ h, const float* __restrict__ ef,
    const float2* __restrict__ pW2, const float* __restrict__ pb,
    const int* __restrict__ src, const int* __restrict__ dst,
    float* __restrict__ s_out, unsigned int* __restrict__ mx_out,
    unsigned int* __restrict__ mn_out, int E)
{
    __shared__ __align__(16) float xs[EPB * KPRE];
    __shared__ int s_src[EPB], s_dst[EPB];
    int tid = threadIdx.x;
    int e0 = blockIdx.x * EPB;
    if (tid < EPB) {
        int ge = e0 + tid;
        s_src[tid] = (ge < E) ? src[ge] : 0;
        s_dst[tid] = (ge < E) ? dst[ge] : 0;
    }
    __syncthreads();
    // stage m_in = [h[src] | h[dst] | edge_feat] into LDS
    for (int idx = tid; idx < EPB * KPRE; idx += 256) {
        int e = idx / KPRE;
        int k = idx - e * KPRE;
        int ge = e0 + e;
        float v = 0.f;
        if (ge < E) {
            if (k < H)            v = h[(size_t)s_src[e] * H + k];
            else if (k < 2 * H)   v = h[(size_t)s_dst[e] * H + (k - H)];
            else                  v = ef[(size_t)ge * EDGE_DIM + (k - 2 * H)];
        }
        xs[idx] = v;
    }
    __syncthreads();
    int c2 = tid & 63;   // channel pair: channels 2*c2, 2*c2+1
    int eg = tid >> 6;   // 0..3 -> edges eg*4 .. eg*4+3
    float acc[4][2] = {};
    const float2* wp = pW2 + c2;
    for (int k = 0; k < KPRE; k += 4) {
        float4 xv[4];
#pragma unroll
        for (int j = 0; j < 4; ++j)
            xv[j] = *(const float4*)&xs[(eg * 4 + j) * KPRE + k];
#pragma unroll
        for (int kk = 0; kk < 4; ++kk) {
            float2 w = wp[(size_t)(k + kk) * 64];
#pragma unroll
            for (int j = 0; j < 4; ++j) {
                float x = ((const float*)&xv[j])[kk];
                acc[j][0] += x * w.x;
                acc[j][1] += x * w.y;
            }
        }
    }
    float b0 = pb[2 * c2], b1 = pb[2 * c2 + 1];
#pragma unroll
    for (int j = 0; j < 4; ++j) {
        int e = eg * 4 + j;
        int ge = e0 + e;
        if (ge >= E) continue;
        int d = s_dst[e];
        float m0 = fmaxf(acc[j][0] + b0, 0.f);
        float m1 = fmaxf(acc[j][1] + b1, 0.f);
        size_t base = (size_t)d * H + 2 * c2;
        atomicAdd(&s_out[base], m0);
        atomicAdd(&s_out[base + 1], m1);
        atomicMax(&mx_out[base], __float_as_uint(m0));
        atomicMax(&mx_out[base + 1], __float_as_uint(m1));
        atomicMin(&mn_out[base], __float_as_uint(m0));
        atomicMin(&mn_out[base + 1], __float_as_uint(m1));
    }
}

// ---------------- posttrans: h += relu(concat(h, scaled) @ qW + qb) ----------------
__global__ __launch_bounds__(256) void k_posttrans(
    float* __restrict__ h,
    const float* __restrict__ s_in, const float* __restrict__ mx_in,
    const float* __restrict__ mn_in,
    const float* __restrict__ deg, const float* __restrict__ invd,
    const float* __restrict__ amp, const float* __restrict__ att,
    const float* __restrict__ qW, const float* __restrict__ qb, int N)
{
    __shared__ __align__(16) float xs[NPB * KPOST];  // 53248 B
    int tid = threadIdx.x;
    int n0 = blockIdx.x * NPB;
    for (int idx = tid; idx < NPB * KPOST; idx += 256) {
        int nl = idx / KPOST;
        int k = idx - nl * KPOST;
        int n = n0 + nl;
        float v = 0.f;
        if (n < N) {
            if (k < H) {
                v = h[(size_t)n * H + k];
            } else {
                int k2 = k - H;
                int grp = k2 >> 9;       // 0: agg, 1: agg*amp, 2: agg*att
                int inner = k2 & 511;
                int comp = inner >> 7;   // 0 mean, 1 max, 2 min, 3 sum
                int c = inner & 127;
                bool he = deg[n] > 0.f;
                float sv = s_in[(size_t)n * H + c];
                float base;
                if (comp == 0)      base = sv * invd[n];
                else if (comp == 1) base = he ? mx_in[(size_t)n * H + c] : 0.f;
                else if (comp == 2) base = he ? mn_in[(size_t)n * H + c] : 0.f;
                else                base = sv;
                float f = (grp == 0) ? 1.f : (grp == 1 ? amp[n] : att[n]);
                v = base * f;
            }
        }
        xs[idx] = v;
    }
    __syncthreads();
    int c = tid & 127;
    int ng = tid >> 7;   // 0/1 -> nodes ng, ng+2, ng+4, ng+6
    float acc[4] = {};
    for (int k = 0; k < KPOST; k += 4) {
        float4 xv[4];
#pragma unroll
        for (int j = 0; j < 4; ++j)
            xv[j] = *(const float4*)&xs[(ng + 2 * j) * KPOST + k];
#pragma unroll
        for (int kk = 0; kk < 4; ++kk) {
            float w = qW[(size_t)(k + kk) * H + c];
#pragma unroll
            for (int j = 0; j < 4; ++j)
                acc[j] += ((const float*)&xv[j])[kk] * w;
        }
    }
    float bb = qb[c];
#pragma unroll
    for (int j = 0; j < 4; ++j) {
        int n = n0 + ng + 2 * j;
        if (n < N)
            h[(size_t)n * H + c] += fmaxf(acc[j] + bb, 0.f);
    }
}

// ---------------- graph readout scatter ----------------
__global__ void k_readout_scatter(const float* __restrict__ h, const int* __restrict__ n2g,
                                  float* __restrict__ g_sum, unsigned int* __restrict__ g_max,
                                  int N) {
    int gid = blockIdx.x * blockDim.x + threadIdx.x;
    int n = gid >> 7, c = gid & 127;
    if (n >= N) return;
    int g = n2g[n];
    float v = h[(size_t)n * H + c];
    atomicAdd(&g_sum[(size_t)g * H + c], v);
    atomicMax(&g_max[(size_t)g * H + c], __float_as_uint(v));
}

__global__ void k_gcnt(const int* __restrict__ n2g, float* __restrict__ g_cnt, int N) {
    int n = blockIdx.x * blockDim.x + threadIdx.x;
    if (n < N) atomicAdd(&g_cnt[n2g[n]], 1.f);
}

// ---------------- final MLP: relu(readout @ W1 + b1) @ W2 + b2 ----------------
__global__ __launch_bounds__(256) void k_final(
    const float* __restrict__ g_sum, const float* __restrict__ g_max,
    const float* __restrict__ g_cnt,
    const float* __restrict__ W1, const float* __restrict__ b1,
    const float* __restrict__ W2, const float* __restrict__ b2,
    float* __restrict__ out)
{
    __shared__ float hid[H];
    int b = blockIdx.x, t = threadIdx.x;
    float cnt = g_cnt[b];
    if (t < H) {
        float acc = 0.f;
        float rc = 1.f / fmaxf(cnt, 1.f);
        for (int k = 0; k < 3 * H; ++k) {
            float x;
            if (k < H)          x = g_sum[(size_t)b * H + k] * rc;
            else if (k < 2 * H) x = (cnt > 0.f) ? g_max[(size_t)b * H + (k - H)] : 0.f;
            else                x = g_sum[(size_t)b * H + (k - 2 * H)];
            acc += x * W1[k * H + t];
        }
        hid[t] = fmaxf(acc + b1[t], 0.f);
    }
    __syncthreads();
    float acc = 0.f;
#pragma unroll 8
    for (int k = 0; k < H; ++k)
        acc += hid[k] * W2[k * T_OUT + t];
    out[(size_t)b * T_OUT + t] = acc + b2[t];
}

extern "C" void kernel_launch(void* const* d_in, const int* in_sizes, int n_in,
                              void* d_out, int out_size, void* d_ws, size_t ws_size,
                              hipStream_t stream) {
    const float* node_feat = (const float*)d_in[0];
    const float* edge_feat = (const float*)d_in[1];
    const float* W_in  = (const float*)d_in[2];
    const float* b_in  = (const float*)d_in[3];
    const float* pre_W = (const float*)d_in[4];
    const float* pre_b = (const float*)d_in[5];
    const float* post_W = (const float*)d_in[6];
    const float* post_b = (const float*)d_in[7];
    const float* out_W1 = (const float*)d_in[8];
    const float* out_b1 = (const float*)d_in[9];
    const float* out_W2 = (const float*)d_in[10];
    const float* out_b2 = (const float*)d_in[11];
    const int* src = (const int*)d_in[12];
    const int* dst = (const int*)d_in[13];
    const int* n2g = (const int*)d_in[14];

    int N = in_sizes[0] / NODE_DIM;
    int E = in_sizes[1] / EDGE_DIM;
    int B = out_size / T_OUT;
    float* out = (float*)d_out;

    float* ws = (float*)d_ws;
    float* h      = ws; ws += (size_t)N * H;
    float* s_buf  = ws; ws += (size_t)N * H;
    unsigned int* mx = (unsigned int*)ws; ws += (size_t)N * H;
    unsigned int* mn = (unsigned int*)ws; ws += (size_t)N * H;
    float* deg  = ws; ws += N;
    float* invd = ws; ws += N;
    float* amp  = ws; ws += N;
    float* att  = ws; ws += N;
    float* g_sum = ws; ws += (size_t)B * H;
    unsigned int* g_max = (unsigned int*)ws; ws += (size_t)B * H;
    float* g_cnt = ws; ws += B;

    // input MLP
    k_input_mlp<<<((size_t)N * H + 255) / 256, 256, 0, stream>>>(node_feat, W_in, b_in, h, N);

    // degree + scalers
    hipMemsetAsync(deg, 0, (size_t)N * sizeof(float), stream);
    k_degree<<<(E + 255) / 256, 256, 0, stream>>>(dst, deg, E);
    k_scalers<<<(N + 255) / 256, 256, 0, stream>>>(deg, invd, amp, att, N);

    for (int l = 0; l < L_DEPTH; ++l) {
        hipMemsetAsync(s_buf, 0,    (size_t)N * H * sizeof(float), stream);
        hipMemsetAsync(mx,    0,    (size_t)N * H * sizeof(float), stream);
        hipMemsetAsync(mn,    0x7F, (size_t)N * H * sizeof(float), stream);
        k_pretrans<<<(E + EPB - 1) / EPB, 256, 0, stream>>>(
            h, edge_feat,
            (const float2*)(pre_W + (size_t)l * KPRE * H), pre_b + (size_t)l * H,
            src, dst, s_buf, mx, mn, E);
        k_posttrans<<<(N + NPB - 1) / NPB, 256, 0, stream>>>(
            h, s_buf, (const float*)mx, (const float*)mn,
            deg, invd, amp, att,
            post_W + (size_t)l * KPOST * H, post_b + (size_t)l * H, N);
    }

    // readout
    hipMemsetAsync(g_sum, 0, (size_t)B * H * sizeof(float), stream);
    hipMemsetAsync(g_max, 0, (size_t)B * H * sizeof(float), stream);
    hipMemsetAsync(g_cnt, 0, (size_t)B * sizeof(float), stream);
    k_readout_scatter<<<((size_t)N * H + 255) / 256, 256, 0, stream>>>(h, n2g, g_sum, g_max, N);
    k_gcnt<<<(N + 255) / 256, 256, 0, stream>>>(n2g, g_cnt, N);
    k_final<<<B, 256, 0, stream>>>(g_sum, (const float*)g_max, g_cnt,
                                   out_W1, out_b1, out_W2, out_b2, out);
}

// Round 2
// 2793.622 us; speedup vs baseline: 2.1353x; 2.1353x over previous
//
#include <hip/hip_runtime.h>

#define H 128
#define NODE_DIM 64
#define EDGE_DIM 32
#define KPOST (13*H)            // 1664
#define T_OUT 256
#define L_DEPTH 5
#define NPB 8                   // nodes per block (posttrans)
#define CHUNK 8                 // edges staged per chunk in k_edge_agg

// ---------------- input MLP: h = relu(node_feat @ W_in + b_in) ----------------
__global__ void k_input_mlp(const float* __restrict__ nf, const float* __restrict__ W,
                            const float* __restrict__ b, float* __restrict__ h, int N) {
    int gid = blockIdx.x * blockDim.x + threadIdx.x;
    int n = gid >> 7, c = gid & 127;
    if (n >= N) return;
    const float* nrow = nf + (size_t)n * NODE_DIM;
    float acc = 0.f;
#pragma unroll 8
    for (int k = 0; k < NODE_DIM; ++k)
        acc += nrow[k] * W[k * H + c];
    acc += b[c];
    h[(size_t)n * H + c] = fmaxf(acc, 0.f);
}

// ---------------- edge sort by dst: histogram, scan, scatter ----------------
__global__ void k_hist(const int* __restrict__ dst, int* __restrict__ deg_i, int E) {
    int e = blockIdx.x * blockDim.x + threadIdx.x;
    if (e < E) atomicAdd(&deg_i[dst[e]], 1);
}

__global__ __launch_bounds__(1024) void k_scan(const int* __restrict__ deg_i,
                                               int* __restrict__ row_start,
                                               int* __restrict__ cursor, int N) {
    __shared__ int part[1024];
    int t = threadIdx.x;
    int per = (N + 1023) / 1024;
    int base = t * per;
    int s = 0;
    for (int i = 0; i < per; ++i) {
        int idx = base + i;
        if (idx < N) s += deg_i[idx];
    }
    part[t] = s;
    __syncthreads();
    for (int off = 1; off < 1024; off <<= 1) {
        int v = (t >= off) ? part[t - off] : 0;
        __syncthreads();
        part[t] += v;
        __syncthreads();
    }
    int run = (t == 0) ? 0 : part[t - 1];
    for (int i = 0; i < per; ++i) {
        int idx = base + i;
        if (idx < N) {
            row_start[idx] = run;
            cursor[idx] = run;
            run += deg_i[idx];
        }
    }
    if (t == 1023) row_start[N] = run;
}

__global__ void k_sortscatter(const int* __restrict__ src, const int* __restrict__ dst,
                              int* __restrict__ cursor, int* __restrict__ es_src,
                              int* __restrict__ es_eid, int E) {
    int e = blockIdx.x * blockDim.x + threadIdx.x;
    if (e >= E) return;
    int pos = atomicAdd(&cursor[dst[e]], 1);
    es_src[pos] = src[e];
    es_eid[pos] = e;
}

// ---------------- degree scalers ----------------
__global__ void k_scalers(const int* __restrict__ deg_i, float* __restrict__ deg,
                          float* __restrict__ invd, float* __restrict__ amp,
                          float* __restrict__ att, int N) {
    int n = blockIdx.x * blockDim.x + threadIdx.x;
    if (n >= N) return;
    float d = (float)deg_i[n];
    deg[n] = d;
    invd[n] = (d > 0.f) ? (1.f / d) : 0.f;
    float ld = logf(d + 1.f);
    amp[n] = ld;                                 // DELTA == 1.0
    att[n] = (d > 0.f) ? (1.f / ld) : 1.f;
}

// ---------------- Y1 = h@W_src, Y2 = h@W_dst (both [N,128]@[128,128]) --------
__global__ __launch_bounds__(256) void k_ygemm(
    const float* __restrict__ h, const float* __restrict__ W1,
    const float* __restrict__ W2, float* __restrict__ Y1,
    float* __restrict__ Y2, int N)
{
    __shared__ float hrow[2][H];
    int slot = threadIdx.x >> 7, c = threadIdx.x & 127;
    int n = blockIdx.x * 2 + slot;
    if (n < N) hrow[slot][c] = h[(size_t)n * H + c];
    __syncthreads();
    if (n >= N) return;
    float a1 = 0.f, a2 = 0.f;
#pragma unroll 4
    for (int k = 0; k < H; ++k) {
        float x = hrow[slot][k];
        a1 += x * W1[k * H + c];
        a2 += x * W2[k * H + c];
    }
    Y1[(size_t)n * H + c] = a1;
    Y2[(size_t)n * H + c] = a2;
}

// ------- aggregation: for each node, reduce relu(Y1[src]+Y2[n]+ef@Wef+pb) -----
__global__ __launch_bounds__(128) void k_edge_agg(
    const float* __restrict__ Y1, const float* __restrict__ Y2,
    const float* __restrict__ ef, const float* __restrict__ Wef,
    const float* __restrict__ pb,
    const int* __restrict__ es_src, const int* __restrict__ es_eid,
    const int* __restrict__ row_start,
    float* __restrict__ s_out, float* __restrict__ mx_out,
    float* __restrict__ mn_out, int N)
{
    __shared__ float wef_s[EDGE_DIM * H];                // 16 KB
    __shared__ __align__(16) float ef_s[CHUNK][EDGE_DIM];// 1 KB
    __shared__ int src_s[CHUNK];
    int n = blockIdx.x;
    int c = threadIdx.x;   // 0..127 channel
    for (int i = c; i < EDGE_DIM * H; i += 128) wef_s[i] = Wef[i];
    int start = row_start[n], end = row_start[n + 1];
    float y2c = Y2[(size_t)n * H + c] + pb[c];
    bool any = end > start;
    float acc_s = 0.f;
    float acc_mx = any ? -3.4e38f : 0.f;
    float acc_mn = any ? 3.4e38f : 0.f;
    __syncthreads();
    for (int p0 = start; p0 < end; p0 += CHUNK) {
        int cnt = min(CHUNK, end - p0);
        if (c < cnt) src_s[c] = es_src[p0 + c];
        for (int i = c; i < cnt * EDGE_DIM; i += 128) {
            int e = i >> 5, k = i & 31;
            ef_s[e][k] = ef[(size_t)es_eid[p0 + e] * EDGE_DIM + k];
        }
        __syncthreads();
        for (int e = 0; e < cnt; ++e) {
            float acc = Y1[(size_t)src_s[e] * H + c] + y2c;
#pragma unroll
            for (int k4 = 0; k4 < EDGE_DIM / 4; ++k4) {
                float4 efv = *(const float4*)&ef_s[e][k4 * 4];
                acc += efv.x * wef_s[(k4 * 4 + 0) * H + c];
                acc += efv.y * wef_s[(k4 * 4 + 1) * H + c];
                acc += efv.z * wef_s[(k4 * 4 + 2) * H + c];
                acc += efv.w * wef_s[(k4 * 4 + 3) * H + c];
            }
            acc = fmaxf(acc, 0.f);
            acc_s += acc;
            acc_mx = fmaxf(acc_mx, acc);
            acc_mn = fminf(acc_mn, acc);
        }
        __syncthreads();
    }
    size_t o = (size_t)n * H + c;
    s_out[o] = acc_s;
    mx_out[o] = acc_mx;
    mn_out[o] = acc_mn;
}

// ---------------- posttrans: h += relu(concat(h, scaled) @ qW + qb) ----------------
__global__ __launch_bounds__(256) void k_posttrans(
    float* __restrict__ h,
    const float* __restrict__ s_in, const float* __restrict__ mx_in,
    const float* __restrict__ mn_in,
    const float* __restrict__ deg, const float* __restrict__ invd,
    const float* __restrict__ amp, const float* __restrict__ att,
    const float* __restrict__ qW, const float* __restrict__ qb, int N)
{
    __shared__ __align__(16) float xs[NPB * KPOST];  // 53248 B
    int tid = threadIdx.x;
    int n0 = blockIdx.x * NPB;
    for (int idx = tid; idx < NPB * KPOST; idx += 256) {
        int nl = idx / KPOST;
        int k = idx - nl * KPOST;
        int n = n0 + nl;
        float v = 0.f;
        if (n < N) {
            if (k < H) {
                v = h[(size_t)n * H + k];
            } else {
                int k2 = k - H;
                int grp = k2 >> 9;       // 0: agg, 1: agg*amp, 2: agg*att
                int inner = k2 & 511;
                int comp = inner >> 7;   // 0 mean, 1 max, 2 min, 3 sum
                int c = inner & 127;
                bool he = deg[n] > 0.f;
                float sv = s_in[(size_t)n * H + c];
                float base;
                if (comp == 0)      base = sv * invd[n];
                else if (comp == 1) base = he ? mx_in[(size_t)n * H + c] : 0.f;
                else if (comp == 2) base = he ? mn_in[(size_t)n * H + c] : 0.f;
                else                base = sv;
                float f = (grp == 0) ? 1.f : (grp == 1 ? amp[n] : att[n]);
                v = base * f;
            }
        }
        xs[idx] = v;
    }
    __syncthreads();
    int c = tid & 127;
    int ng = tid >> 7;
    float acc[4] = {};
    for (int k = 0; k < KPOST; k += 4) {
        float4 xv[4];
#pragma unroll
        for (int j = 0; j < 4; ++j)
            xv[j] = *(const float4*)&xs[(ng + 2 * j) * KPOST + k];
#pragma unroll
        for (int kk = 0; kk < 4; ++kk) {
            float w = qW[(size_t)(k + kk) * H + c];
#pragma unroll
            for (int j = 0; j < 4; ++j)
                acc[j] += ((const float*)&xv[j])[kk] * w;
        }
    }
    float bb = qb[c];
#pragma unroll
    for (int j = 0; j < 4; ++j) {
        int n = n0 + ng + 2 * j;
        if (n < N)
            h[(size_t)n * H + c] += fmaxf(acc[j] + bb, 0.f);
    }
}

// ---------------- graph readout scatter ----------------
__global__ void k_readout_scatter(const float* __restrict__ h, const int* __restrict__ n2g,
                                  float* __restrict__ g_sum, unsigned int* __restrict__ g_max,
                                  int N) {
    int gid = blockIdx.x * blockDim.x + threadIdx.x;
    int n = gid >> 7, c = gid & 127;
    if (n >= N) return;
    int g = n2g[n];
    float v = h[(size_t)n * H + c];
    atomicAdd(&g_sum[(size_t)g * H + c], v);
    atomicMax(&g_max[(size_t)g * H + c], __float_as_uint(v));  // h >= 0 always
}

__global__ void k_gcnt(const int* __restrict__ n2g, float* __restrict__ g_cnt, int N) {
    int n = blockIdx.x * blockDim.x + threadIdx.x;
    if (n < N) atomicAdd(&g_cnt[n2g[n]], 1.f);
}

// ---------------- final MLP ----------------
__global__ __launch_bounds__(256) void k_final(
    const float* __restrict__ g_sum, const float* __restrict__ g_max,
    const float* __restrict__ g_cnt,
    const float* __restrict__ W1, const float* __restrict__ b1,
    const float* __restrict__ W2, const float* __restrict__ b2,
    float* __restrict__ out)
{
    __shared__ float hid[H];
    int b = blockIdx.x, t = threadIdx.x;
    float cnt = g_cnt[b];
    if (t < H) {
        float acc = 0.f;
        float rc = 1.f / fmaxf(cnt, 1.f);
        for (int k = 0; k < 3 * H; ++k) {
            float x;
            if (k < H)          x = g_sum[(size_t)b * H + k] * rc;
            else if (k < 2 * H) x = (cnt > 0.f) ? g_max[(size_t)b * H + (k - H)] : 0.f;
            else                x = g_sum[(size_t)b * H + (k - 2 * H)];
            acc += x * W1[k * H + t];
        }
        hid[t] = fmaxf(acc + b1[t], 0.f);
    }
    __syncthreads();
    float acc = 0.f;
#pragma unroll 8
    for (int k = 0; k < H; ++k)
        acc += hid[k] * W2[k * T_OUT + t];
    out[(size_t)b * T_OUT + t] = acc + b2[t];
}

extern "C" void kernel_launch(void* const* d_in, const int* in_sizes, int n_in,
                              void* d_out, int out_size, void* d_ws, size_t ws_size,
                              hipStream_t stream) {
    const float* node_feat = (const float*)d_in[0];
    const float* edge_feat = (const float*)d_in[1];
    const float* W_in  = (const float*)d_in[2];
    const float* b_in  = (const float*)d_in[3];
    const float* pre_W = (const float*)d_in[4];
    const float* pre_b = (const float*)d_in[5];
    const float* post_W = (const float*)d_in[6];
    const float* post_b = (const float*)d_in[7];
    const float* out_W1 = (const float*)d_in[8];
    const float* out_b1 = (const float*)d_in[9];
    const float* out_W2 = (const float*)d_in[10];
    const float* out_b2 = (const float*)d_in[11];
    const int* src = (const int*)d_in[12];
    const int* dst = (const int*)d_in[13];
    const int* n2g = (const int*)d_in[14];

    int N = in_sizes[0] / NODE_DIM;
    int E = in_sizes[1] / EDGE_DIM;
    int B = out_size / T_OUT;
    float* out = (float*)d_out;

    float* ws = (float*)d_ws;
    float* h      = ws; ws += (size_t)N * H;
    float* s_buf  = ws; ws += (size_t)N * H;
    float* mx     = ws; ws += (size_t)N * H;
    float* mn     = ws; ws += (size_t)N * H;
    float* Y1     = ws; ws += (size_t)N * H;
    float* Y2     = ws; ws += (size_t)N * H;
    float* deg  = ws; ws += N;
    float* invd = ws; ws += N;
    float* amp  = ws; ws += N;
    float* att  = ws; ws += N;
    float* g_sum = ws; ws += (size_t)B * H;
    unsigned int* g_max = (unsigned int*)ws; ws += (size_t)B * H;
    float* g_cnt = ws; ws += B;
    int* deg_i     = (int*)ws; ws += N;
    int* row_start = (int*)ws; ws += N + 1;
    int* cursor    = (int*)ws; ws += N;
    int* es_src    = (int*)ws; ws += E;
    int* es_eid    = (int*)ws; ws += E;

    const int KPRE = 2 * H + EDGE_DIM;  // 288

    // input MLP
    k_input_mlp<<<((size_t)N * H + 255) / 256, 256, 0, stream>>>(node_feat, W_in, b_in, h, N);

    // edge sort by dst (dst static across layers)
    hipMemsetAsync(deg_i, 0, (size_t)N * sizeof(int), stream);
    k_hist<<<(E + 255) / 256, 256, 0, stream>>>(dst, deg_i, E);
    k_scan<<<1, 1024, 0, stream>>>(deg_i, row_start, cursor, N);
    k_sortscatter<<<(E + 255) / 256, 256, 0, stream>>>(src, dst, cursor, es_src, es_eid, E);
    k_scalers<<<(N + 255) / 256, 256, 0, stream>>>(deg_i, deg, invd, amp, att, N);

    for (int l = 0; l < L_DEPTH; ++l) {
        const float* pW = pre_W + (size_t)l * KPRE * H;
        k_ygemm<<<(N + 1) / 2, 256, 0, stream>>>(h, pW, pW + (size_t)H * H, Y1, Y2, N);
        k_edge_agg<<<N, 128, 0, stream>>>(
            Y1, Y2, edge_feat, pW + (size_t)2 * H * H, pre_b + (size_t)l * H,
            es_src, es_eid, row_start, s_buf, mx, mn, N);
        k_posttrans<<<(N + NPB - 1) / NPB, 256, 0, stream>>>(
            h, s_buf, mx, mn, deg, invd, amp, att,
            post_W + (size_t)l * KPOST * H, post_b + (size_t)l * H, N);
    }

    // readout
    hipMemsetAsync(g_sum, 0, (size_t)B * H * sizeof(float), stream);
    hipMemsetAsync(g_max, 0, (size_t)B * H * sizeof(float), stream);
    hipMemsetAsync(g_cnt, 0, (size_t)B * sizeof(float), stream);
    k_readout_scatter<<<((size_t)N * H + 255) / 256, 256, 0, stream>>>(h, n2g, g_sum, g_max, N);
    k_gcnt<<<(N + 255) / 256, 256, 0, stream>>>(n2g, g_cnt, N);
    k_final<<<B, 256, 0, stream>>>(g_sum, (const float*)g_max, g_cnt,
                                   out_W1, out_b1, out_W2, out_b2, out);
}

// Round 3
// 1303.071 us; speedup vs baseline: 4.5779x; 2.1439x over previous
//
#include <hip/hip_runtime.h>

#define H 128
#define NODE_DIM 64
#define EDGE_DIM 32
#define KPOST (13*H)            // 1664
#define T_OUT 256
#define L_DEPTH 5
#define CHUNK 8                 // edges staged per chunk in k_edge_agg

typedef short short8v __attribute__((ext_vector_type(8)));
typedef float float4v __attribute__((ext_vector_type(4)));

__device__ __forceinline__ unsigned short f2bf(float x) {
    unsigned int b = __float_as_uint(x);
    return (unsigned short)((b + 0x7fffu + ((b >> 16) & 1u)) >> 16);  // RNE
}

// ---------------- input MLP: h = relu(node_feat @ W_in + b_in) ----------------
__global__ void k_input_mlp(const float* __restrict__ nf, const float* __restrict__ W,
                            const float* __restrict__ b, float* __restrict__ h, int N) {
    int gid = blockIdx.x * blockDim.x + threadIdx.x;
    int n = gid >> 7, c = gid & 127;
    if (n >= N) return;
    const float* nrow = nf + (size_t)n * NODE_DIM;
    float acc = 0.f;
#pragma unroll 8
    for (int k = 0; k < NODE_DIM; ++k)
        acc += nrow[k] * W[k * H + c];
    acc += b[c];
    h[(size_t)n * H + c] = fmaxf(acc, 0.f);
}

// ---------------- edge sort by dst: histogram, scan, scatter ----------------
__global__ void k_hist(const int* __restrict__ dst, int* __restrict__ deg_i, int E) {
    int e = blockIdx.x * blockDim.x + threadIdx.x;
    if (e < E) atomicAdd(&deg_i[dst[e]], 1);
}

__global__ __launch_bounds__(1024) void k_scan(const int* __restrict__ deg_i,
                                               int* __restrict__ row_start,
                                               int* __restrict__ cursor, int N) {
    __shared__ int part[1024];
    int t = threadIdx.x;
    int per = (N + 1023) / 1024;
    int base = t * per;
    int s = 0;
    for (int i = 0; i < per; ++i) {
        int idx = base + i;
        if (idx < N) s += deg_i[idx];
    }
    part[t] = s;
    __syncthreads();
    for (int off = 1; off < 1024; off <<= 1) {
        int v = (t >= off) ? part[t - off] : 0;
        __syncthreads();
        part[t] += v;
        __syncthreads();
    }
    int run = (t == 0) ? 0 : part[t - 1];
    for (int i = 0; i < per; ++i) {
        int idx = base + i;
        if (idx < N) {
            row_start[idx] = run;
            cursor[idx] = run;
            run += deg_i[idx];
        }
    }
    if (t == 1023) row_start[N] = run;
}

__global__ void k_sortscatter(const int* __restrict__ src, const int* __restrict__ dst,
                              int* __restrict__ cursor, int* __restrict__ es_src,
                              int* __restrict__ es_eid, int E) {
    int e = blockIdx.x * blockDim.x + threadIdx.x;
    if (e >= E) return;
    int pos = atomicAdd(&cursor[dst[e]], 1);
    es_src[pos] = src[e];
    es_eid[pos] = e;
}

// ---------------- degree scalers ----------------
__global__ void k_scalers(const int* __restrict__ deg_i, float* __restrict__ invd,
                          float* __restrict__ amp, float* __restrict__ att, int N) {
    int n = blockIdx.x * blockDim.x + threadIdx.x;
    if (n >= N) return;
    float d = (float)deg_i[n];
    invd[n] = (d > 0.f) ? (1.f / d) : 0.f;
    float ld = logf(d + 1.f);
    amp[n] = ld;                                 // DELTA == 1.0
    att[n] = (d > 0.f) ? (1.f / ld) : 1.f;
}

// ---------------- weight converters: fp32 -> bf16 fragment-order ----------------
// posttrans W: [1664][128] -> frag layout ((kglob*8+cb)*64+lane)*8+j,
// col = cb*16+(lane&15), k = kglob*32+(lane>>4)*8+j
__global__ void k_wconv_post(const float* __restrict__ qW, short* __restrict__ Wf) {
    int t = blockIdx.x * 256 + threadIdx.x;
    if (t >= 52 * 8 * 64) return;
    int lane = t & 63, fc = t >> 6;
    int kglob = fc >> 3, cb = fc & 7;
    int col = cb * 16 + (lane & 15);
    int k0 = kglob * 32 + ((lane >> 4) << 3);
    short8v o;
#pragma unroll
    for (int j = 0; j < 8; ++j)
        o[j] = (short)f2bf(qW[(size_t)(k0 + j) * H + col]);
    *(short8v*)(Wf + (size_t)t * 8) = o;
}

// ygemm W: cols 0..127 from pW rows 0..127 (W_src), cols 128..255 from rows 128..255 (W_dst)
__global__ void k_wconv_y(const float* __restrict__ pW, short* __restrict__ Wf) {
    int t = blockIdx.x * 256 + threadIdx.x;
    if (t >= 4 * 16 * 64) return;
    int lane = t & 63, fc = t >> 6;
    int kglob = fc >> 4, cb = fc & 15;
    int col = cb * 16 + (lane & 15);          // 0..255
    int k0 = kglob * 32 + ((lane >> 4) << 3); // 0..127
    int rowoff = (col < 128) ? 0 : 128;
    int c = col & 127;
    short8v o;
#pragma unroll
    for (int j = 0; j < 8; ++j)
        o[j] = (short)f2bf(pW[(size_t)(rowoff + k0 + j) * H + c]);
    *(short8v*)(Wf + (size_t)t * 8) = o;
}

// ---------------- Y1 = h@W_src, Y2 = h@W_dst via MFMA ----------------
__global__ __launch_bounds__(256) void k_ygemm_mfma(
    const float* __restrict__ h, const short* __restrict__ Wf,
    float* __restrict__ Y1, float* __restrict__ Y2, int N)
{
    __shared__ __align__(16) short Xs[64 * 128];   // 16 KB, XOR-swizzled
    int tid = threadIdx.x;
    int n0 = blockIdx.x * 64;
    int lane = tid & 63, wave = tid >> 6;
    float4v acc[16];
#pragma unroll
    for (int cb = 0; cb < 16; ++cb) acc[cb] = (float4v){0.f, 0.f, 0.f, 0.f};

    int rs = tid >> 4, c0 = (tid & 15) * 8;
#pragma unroll
    for (int j = 0; j < 4; ++j) {
        int r = rs + j * 16;
        int n = n0 + r;
        float4 v0 = {}, v1 = {};
        if (n < N) {
            const float* p = h + (size_t)n * H + c0;
            v0 = *(const float4*)p;
            v1 = *(const float4*)(p + 4);
        }
        short8v o;
        o[0] = (short)f2bf(v0.x); o[1] = (short)f2bf(v0.y);
        o[2] = (short)f2bf(v0.z); o[3] = (short)f2bf(v0.w);
        o[4] = (short)f2bf(v1.x); o[5] = (short)f2bf(v1.y);
        o[6] = (short)f2bf(v1.z); o[7] = (short)f2bf(v1.w);
        *(short8v*)((char*)Xs + r * 256 + ((c0 * 2) ^ ((r & 7) << 4))) = o;
    }
    __syncthreads();
    int rloc = wave * 16 + (lane & 15);
    int swz = (rloc & 7) << 4;
#pragma unroll
    for (int ks = 0; ks < 4; ++ks) {
        int boff = rloc * 256 + (((ks * 64) + ((lane >> 4) << 4)) ^ swz);
        short8v a = *(short8v*)((char*)Xs + boff);
        const short* wp = Wf + ((size_t)(ks * 16) * 64 + lane) * 8;
#pragma unroll
        for (int cb = 0; cb < 16; ++cb) {
            short8v b = *(const short8v*)(wp + (size_t)cb * 512);
            acc[cb] = __builtin_amdgcn_mfma_f32_16x16x32_bf16(a, b, acc[cb], 0, 0, 0);
        }
    }
    int col0 = lane & 15;
    int row0 = wave * 16 + ((lane >> 4) << 2);
#pragma unroll
    for (int cb = 0; cb < 16; ++cb) {
        int col = cb * 16 + col0;
        float* dst = (col < 128) ? Y1 : Y2;
        int c = col & 127;
#pragma unroll
        for (int r = 0; r < 4; ++r) {
            int n = n0 + row0 + r;
            if (n < N) dst[(size_t)n * H + c] = acc[cb][r];
        }
    }
}

// ------- aggregation: for each node, reduce relu(Y1[src]+Y2[n]+ef@Wef+pb) -----
__global__ __launch_bounds__(128) void k_edge_agg(
    const float* __restrict__ Y1, const float* __restrict__ Y2,
    const float* __restrict__ ef, const float* __restrict__ Wef,
    const float* __restrict__ pb,
    const int* __restrict__ es_src, const int* __restrict__ es_eid,
    const int* __restrict__ row_start,
    float* __restrict__ s_out, float* __restrict__ mx_out,
    float* __restrict__ mn_out, int N)
{
    __shared__ float wef_s[EDGE_DIM * H];                // 16 KB
    __shared__ __align__(16) float ef_s[CHUNK][EDGE_DIM];// 1 KB
    __shared__ int src_s[CHUNK];
    int n = blockIdx.x;
    int c = threadIdx.x;   // 0..127 channel
    for (int i = c; i < EDGE_DIM * H; i += 128) wef_s[i] = Wef[i];
    int start = row_start[n], end = row_start[n + 1];
    float y2c = Y2[(size_t)n * H + c] + pb[c];
    bool any = end > start;
    float acc_s = 0.f;
    float acc_mx = any ? -3.4e38f : 0.f;
    float acc_mn = any ? 3.4e38f : 0.f;
    __syncthreads();
    for (int p0 = start; p0 < end; p0 += CHUNK) {
        int cnt = min(CHUNK, end - p0);
        if (c < cnt) src_s[c] = es_src[p0 + c];
        for (int i = c; i < cnt * EDGE_DIM; i += 128) {
            int e = i >> 5, k = i & 31;
            ef_s[e][k] = ef[(size_t)es_eid[p0 + e] * EDGE_DIM + k];
        }
        __syncthreads();
        for (int e = 0; e < cnt; ++e) {
            float acc = Y1[(size_t)src_s[e] * H + c] + y2c;
#pragma unroll
            for (int k4 = 0; k4 < EDGE_DIM / 4; ++k4) {
                float4 efv = *(const float4*)&ef_s[e][k4 * 4];
                acc += efv.x * wef_s[(k4 * 4 + 0) * H + c];
                acc += efv.y * wef_s[(k4 * 4 + 1) * H + c];
                acc += efv.z * wef_s[(k4 * 4 + 2) * H + c];
                acc += efv.w * wef_s[(k4 * 4 + 3) * H + c];
            }
            acc = fmaxf(acc, 0.f);
            acc_s += acc;
            acc_mx = fmaxf(acc_mx, acc);
            acc_mn = fminf(acc_mn, acc);
        }
        __syncthreads();
    }
    size_t o = (size_t)n * H + c;
    s_out[o] = acc_s;
    mx_out[o] = acc_mx;
    mn_out[o] = acc_mn;
}

// ---------------- posttrans via MFMA: h += relu(X @ qW + qb) ----------------
// X[n, k] built on the fly: kb=0 -> h; kb=1..12 -> comp in {mean,max,min,sum} x grp scaler
__global__ __launch_bounds__(256) void k_post_mfma(
    float* __restrict__ h,
    const float* __restrict__ s_in, const float* __restrict__ mx_in,
    const float* __restrict__ mn_in,
    const float* __restrict__ invd, const float* __restrict__ amp,
    const float* __restrict__ att,
    const short* __restrict__ Wf, const float* __restrict__ qb, int N)
{
    __shared__ __align__(16) short Xs[64 * 128];   // 16 KB, XOR-swizzled
    __shared__ float scal[3][64];
    int tid = threadIdx.x;
    int n0 = blockIdx.x * 64;
    int lane = tid & 63, wave = tid >> 6;

    if (tid < 192) {
        int which = tid >> 6, r = tid & 63;
        int n = n0 + r;
        const float* sp = (which == 0) ? invd : (which == 1 ? amp : att);
        scal[which][r] = (n < N) ? sp[n] : 0.f;
    }

    float4v acc[8];
#pragma unroll
    for (int cb = 0; cb < 8; ++cb) acc[cb] = (float4v){0.f, 0.f, 0.f, 0.f};

    int rs = tid >> 4;           // staging row base 0..15
    int c0 = (tid & 15) * 8;     // staging col base (floats)

    for (int kb = 0; kb < 13; ++kb) {
        const float* srcp;
        int comp = 0, grp = 0;
        if (kb == 0) {
            srcp = h;
        } else {
            comp = (kb - 1) & 3;          // 0 mean, 1 max, 2 min, 3 sum
            grp  = (kb - 1) >> 2;         // 0: x1, 1: x amp, 2: x att
            srcp = (comp == 1) ? mx_in : (comp == 2 ? mn_in : s_in);
        }
#pragma unroll
        for (int j = 0; j < 4; ++j) {
            int r = rs + j * 16;
            int n = n0 + r;
            float4 v0 = {}, v1 = {};
            if (n < N) {
                const float* p = srcp + (size_t)n * H + c0;
                v0 = *(const float4*)p;
                v1 = *(const float4*)(p + 4);
            }
            float f = 1.f;
            if (kb != 0) {
                f = (grp == 0) ? 1.f : scal[grp][r];
                if (comp == 0) f *= scal[0][r];
            }
            short8v o;
            o[0] = (short)f2bf(v0.x * f); o[1] = (short)f2bf(v0.y * f);
            o[2] = (short)f2bf(v0.z * f); o[3] = (short)f2bf(v0.w * f);
            o[4] = (short)f2bf(v1.x * f); o[5] = (short)f2bf(v1.y * f);
            o[6] = (short)f2bf(v1.z * f); o[7] = (short)f2bf(v1.w * f);
            *(short8v*)((char*)Xs + r * 256 + ((c0 * 2) ^ ((r & 7) << 4))) = o;
        }
        __syncthreads();
        int rloc = wave * 16 + (lane & 15);
        int swz = (rloc & 7) << 4;
#pragma unroll
        for (int ks = 0; ks < 4; ++ks) {
            int boff = rloc * 256 + (((ks * 64) + ((lane >> 4) << 4)) ^ swz);
            short8v a = *(short8v*)((char*)Xs + boff);
            const short* wp = Wf + ((size_t)((kb * 4 + ks) * 8) * 64 + lane) * 8;
#pragma unroll
            for (int cb = 0; cb < 8; ++cb) {
                short8v b = *(const short8v*)(wp + (size_t)cb * 512);
                acc[cb] = __builtin_amdgcn_mfma_f32_16x16x32_bf16(a, b, acc[cb], 0, 0, 0);
            }
        }
        __syncthreads();
    }
    int col0 = lane & 15;
    int row0 = wave * 16 + ((lane >> 4) << 2);
#pragma unroll
    for (int cb = 0; cb < 8; ++cb) {
        int col = cb * 16 + col0;
        float bb = qb[col];
#pragma unroll
        for (int r = 0; r < 4; ++r) {
            int n = n0 + row0 + r;
            if (n < N)
                h[(size_t)n * H + col] += fmaxf(acc[cb][r] + bb, 0.f);
        }
    }
}

// ---------------- graph readout scatter ----------------
__global__ void k_readout_scatter(const float* __restrict__ h, const int* __restrict__ n2g,
                                  float* __restrict__ g_sum, unsigned int* __restrict__ g_max,
                                  int N) {
    int gid = blockIdx.x * blockDim.x + threadIdx.x;
    int n = gid >> 7, c = gid & 127;
    if (n >= N) return;
    int g = n2g[n];
    float v = h[(size_t)n * H + c];
    atomicAdd(&g_sum[(size_t)g * H + c], v);
    atomicMax(&g_max[(size_t)g * H + c], __float_as_uint(v));  // h >= 0 always
}

__global__ void k_gcnt(const int* __restrict__ n2g, float* __restrict__ g_cnt, int N) {
    int n = blockIdx.x * blockDim.x + threadIdx.x;
    if (n < N) atomicAdd(&g_cnt[n2g[n]], 1.f);
}

// ---------------- final MLP ----------------
__global__ __launch_bounds__(256) void k_final(
    const float* __restrict__ g_sum, const float* __restrict__ g_max,
    const float* __restrict__ g_cnt,
    const float* __restrict__ W1, const float* __restrict__ b1,
    const float* __restrict__ W2, const float* __restrict__ b2,
    float* __restrict__ out)
{
    __shared__ float hid[H];
    int b = blockIdx.x, t = threadIdx.x;
    float cnt = g_cnt[b];
    if (t < H) {
        float acc = 0.f;
        float rc = 1.f / fmaxf(cnt, 1.f);
        for (int k = 0; k < 3 * H; ++k) {
            float x;
            if (k < H)          x = g_sum[(size_t)b * H + k] * rc;
            else if (k < 2 * H) x = (cnt > 0.f) ? g_max[(size_t)b * H + (k - H)] : 0.f;
            else                x = g_sum[(size_t)b * H + (k - 2 * H)];
            acc += x * W1[k * H + t];
        }
        hid[t] = fmaxf(acc + b1[t], 0.f);
    }
    __syncthreads();
    float acc = 0.f;
#pragma unroll 8
    for (int k = 0; k < H; ++k)
        acc += hid[k] * W2[k * T_OUT + t];
    out[(size_t)b * T_OUT + t] = acc + b2[t];
}

extern "C" void kernel_launch(void* const* d_in, const int* in_sizes, int n_in,
                              void* d_out, int out_size, void* d_ws, size_t ws_size,
                              hipStream_t stream) {
    const float* node_feat = (const float*)d_in[0];
    const float* edge_feat = (const float*)d_in[1];
    const float* W_in  = (const float*)d_in[2];
    const float* b_in  = (const float*)d_in[3];
    const float* pre_W = (const float*)d_in[4];
    const float* pre_b = (const float*)d_in[5];
    const float* post_W = (const float*)d_in[6];
    const float* post_b = (const float*)d_in[7];
    const float* out_W1 = (const float*)d_in[8];
    const float* out_b1 = (const float*)d_in[9];
    const float* out_W2 = (const float*)d_in[10];
    const float* out_b2 = (const float*)d_in[11];
    const int* src = (const int*)d_in[12];
    const int* dst = (const int*)d_in[13];
    const int* n2g = (const int*)d_in[14];

    int N = in_sizes[0] / NODE_DIM;
    int E = in_sizes[1] / EDGE_DIM;
    int B = out_size / T_OUT;
    float* out = (float*)d_out;

    float* ws = (float*)d_ws;
    float* h      = ws; ws += (size_t)N * H;
    float* s_buf  = ws; ws += (size_t)N * H;
    float* mx     = ws; ws += (size_t)N * H;
    float* mn     = ws; ws += (size_t)N * H;
    float* Y1     = ws; ws += (size_t)N * H;
    float* Y2     = ws; ws += (size_t)N * H;
    float* invd = ws; ws += N;
    float* amp  = ws; ws += N;
    float* att  = ws; ws += N;
    float* g_sum = ws; ws += (size_t)B * H;
    unsigned int* g_max = (unsigned int*)ws; ws += (size_t)B * H;
    float* g_cnt = ws; ws += B;
    int* deg_i     = (int*)ws; ws += N;
    int* row_start = (int*)ws; ws += N + 1;
    int* cursor    = (int*)ws; ws += N;
    int* es_src    = (int*)ws; ws += E;
    int* es_eid    = (int*)ws; ws += E;
    short* wf_post = (short*)ws; ws += (52 * 8 * 64 * 8) / 2;   // 212992 shorts
    short* wf_y    = (short*)ws; ws += (4 * 16 * 64 * 8) / 2;   // 32768 shorts

    const int KPRE = 2 * H + EDGE_DIM;  // 288

    // input MLP
    k_input_mlp<<<((size_t)N * H + 255) / 256, 256, 0, stream>>>(node_feat, W_in, b_in, h, N);

    // edge sort by dst (dst static across layers)
    hipMemsetAsync(deg_i, 0, (size_t)N * sizeof(int), stream);
    k_hist<<<(E + 255) / 256, 256, 0, stream>>>(dst, deg_i, E);
    k_scan<<<1, 1024, 0, stream>>>(deg_i, row_start, cursor, N);
    k_sortscatter<<<(E + 255) / 256, 256, 0, stream>>>(src, dst, cursor, es_src, es_eid, E);
    k_scalers<<<(N + 255) / 256, 256, 0, stream>>>(deg_i, invd, amp, att, N);

    for (int l = 0; l < L_DEPTH; ++l) {
        const float* pW = pre_W + (size_t)l * KPRE * H;
        k_wconv_y<<<16, 256, 0, stream>>>(pW, wf_y);
        k_wconv_post<<<104, 256, 0, stream>>>(post_W + (size_t)l * KPOST * H, wf_post);
        k_ygemm_mfma<<<(N + 63) / 64, 256, 0, stream>>>(h, wf_y, Y1, Y2, N);
        k_edge_agg<<<N, 128, 0, stream>>>(
            Y1, Y2, edge_feat, pW + (size_t)2 * H * H, pre_b + (size_t)l * H,
            es_src, es_eid, row_start, s_buf, mx, mn, N);
        k_post_mfma<<<(N + 63) / 64, 256, 0, stream>>>(
            h, s_buf, mx, mn, invd, amp, att, wf_post, post_b + (size_t)l * H, N);
    }

    // readout
    hipMemsetAsync(g_sum, 0, (size_t)B * H * sizeof(float), stream);
    hipMemsetAsync(g_max, 0, (size_t)B * H * sizeof(float), stream);
    hipMemsetAsync(g_cnt, 0, (size_t)B * sizeof(float), stream);
    k_readout_scatter<<<((size_t)N * H + 255) / 256, 256, 0, stream>>>(h, n2g, g_sum, g_max, N);
    k_gcnt<<<(N + 255) / 256, 256, 0, stream>>>(n2g, g_cnt, N);
    k_final<<<B, 256, 0, stream>>>(g_sum, (const float*)g_max, g_cnt,
                                   out_W1, out_b1, out_W2, out_b2, out);
}

// Round 4
// 1044.687 us; speedup vs baseline: 5.7101x; 1.2473x over previous
//
#include <hip/hip_runtime.h>

#define H 128
#define NODE_DIM 64
#define EDGE_DIM 32
#define KPRE (2*H + EDGE_DIM)   // 288
#define KPOST (13*H)            // 1664
#define T_OUT 256
#define L_DEPTH 5
#define POST_FRAGS (52*8*64)    // fragment-chunks per layer (posttrans W)
#define Y_FRAGS (4*16*64)       // fragment-chunks per layer (ygemm W)

typedef short short8v __attribute__((ext_vector_type(8)));
typedef float float4v __attribute__((ext_vector_type(4)));

__device__ __forceinline__ unsigned short f2bf(float x) {
    unsigned int b = __float_as_uint(x);
    return (unsigned short)((b + 0x7fffu + ((b >> 16) & 1u)) >> 16);  // RNE
}

// ---------------- input MLP: h = relu(node_feat @ W_in + b_in) ----------------
__global__ void k_input_mlp(const float* __restrict__ nf, const float* __restrict__ W,
                            const float* __restrict__ b, float* __restrict__ h, int N) {
    int gid = blockIdx.x * blockDim.x + threadIdx.x;
    int n = gid >> 7, c = gid & 127;
    if (n >= N) return;
    const float* nrow = nf + (size_t)n * NODE_DIM;
    float acc = 0.f;
#pragma unroll 8
    for (int k = 0; k < NODE_DIM; ++k)
        acc += nrow[k] * W[k * H + c];
    acc += b[c];
    h[(size_t)n * H + c] = fmaxf(acc, 0.f);
}

// ---------------- edge sort by dst: histogram, scan, scatter ----------------
__global__ void k_hist(const int* __restrict__ dst, int* __restrict__ deg_i, int E) {
    int e = blockIdx.x * blockDim.x + threadIdx.x;
    if (e < E) atomicAdd(&deg_i[dst[e]], 1);
}

__global__ __launch_bounds__(1024) void k_scan(const int* __restrict__ deg_i,
                                               int* __restrict__ row_start,
                                               int* __restrict__ cursor, int N) {
    __shared__ int part[1024];
    int t = threadIdx.x;
    int per = (N + 1023) / 1024;
    int base = t * per;
    int s = 0;
    for (int i = 0; i < per; ++i) {
        int idx = base + i;
        if (idx < N) s += deg_i[idx];
    }
    part[t] = s;
    __syncthreads();
    for (int off = 1; off < 1024; off <<= 1) {
        int v = (t >= off) ? part[t - off] : 0;
        __syncthreads();
        part[t] += v;
        __syncthreads();
    }
    int run = (t == 0) ? 0 : part[t - 1];
    for (int i = 0; i < per; ++i) {
        int idx = base + i;
        if (idx < N) {
            row_start[idx] = run;
            cursor[idx] = run;
            run += deg_i[idx];
        }
    }
    if (t == 1023) row_start[N] = run;
}

__global__ void k_sortscatter(const int* __restrict__ src, const int* __restrict__ dst,
                              int* __restrict__ cursor, int* __restrict__ es_src,
                              int* __restrict__ es_eid, int E) {
    int e = blockIdx.x * blockDim.x + threadIdx.x;
    if (e >= E) return;
    int pos = atomicAdd(&cursor[dst[e]], 1);
    es_src[pos] = src[e];
    es_eid[pos] = e;
}

// ---------------- degree scalers ----------------
__global__ void k_scalers(const int* __restrict__ deg_i, float* __restrict__ invd,
                          float* __restrict__ amp, float* __restrict__ att, int N) {
    int n = blockIdx.x * blockDim.x + threadIdx.x;
    if (n >= N) return;
    float d = (float)deg_i[n];
    invd[n] = (d > 0.f) ? (1.f / d) : 0.f;
    float ld = logf(d + 1.f);
    amp[n] = ld;                                 // DELTA == 1.0
    att[n] = (d > 0.f) ? (1.f / ld) : 1.f;
}

// ------- weight conversion, ALL layers at once (weights static per call) -------
// post W: [1664][128] -> frag ((kglob*8+cb)*64+lane)*8+j, col=cb*16+(lane&15),
//         k = kglob*32+(lane>>4)*8+j
// y W:    cols 0..127 = W_src rows, cols 128..255 = W_dst rows
__global__ void k_wconv_all(const float* __restrict__ pre_W,
                            const float* __restrict__ post_W,
                            short* __restrict__ wf_y_all,
                            short* __restrict__ wf_post_all) {
    int t = blockIdx.x * 256 + threadIdx.x;
    if (t < L_DEPTH * POST_FRAGS) {
        int l = t / POST_FRAGS, tt = t - l * POST_FRAGS;
        const float* qW = post_W + (size_t)l * KPOST * H;
        int lane = tt & 63, fc = tt >> 6;
        int kglob = fc >> 3, cb = fc & 7;
        int col = cb * 16 + (lane & 15);
        int k0 = kglob * 32 + ((lane >> 4) << 3);
        short8v o;
#pragma unroll
        for (int j = 0; j < 8; ++j)
            o[j] = (short)f2bf(qW[(size_t)(k0 + j) * H + col]);
        *(short8v*)(wf_post_all + (size_t)t * 8) = o;
        return;
    }
    t -= L_DEPTH * POST_FRAGS;
    if (t >= L_DEPTH * Y_FRAGS) return;
    int l = t / Y_FRAGS, tt = t - l * Y_FRAGS;
    const float* pW = pre_W + (size_t)l * KPRE * H;
    int lane = tt & 63, fc = tt >> 6;
    int kglob = fc >> 4, cb = fc & 15;
    int col = cb * 16 + (lane & 15);          // 0..255
    int k0 = kglob * 32 + ((lane >> 4) << 3); // 0..127
    int rowoff = (col < 128) ? 0 : 128;
    int c = col & 127;
    short8v o;
#pragma unroll
    for (int j = 0; j < 8; ++j)
        o[j] = (short)f2bf(pW[(size_t)(rowoff + k0 + j) * H + c]);
    *(short8v*)(wf_y_all + ((size_t)l * Y_FRAGS + tt) * 8) = o;
}

// ---------------- Y1 = h@W_src, Y2 = h@W_dst via MFMA ----------------
__global__ __launch_bounds__(256) void k_ygemm_mfma(
    const float* __restrict__ h, const short* __restrict__ Wf,
    float* __restrict__ Y1, float* __restrict__ Y2, int N)
{
    __shared__ __align__(16) short Xs[64 * 128];   // 16 KB, XOR-swizzled
    int tid = threadIdx.x;
    int n0 = blockIdx.x * 64;
    int lane = tid & 63, wave = tid >> 6;
    float4v acc[16];
#pragma unroll
    for (int cb = 0; cb < 16; ++cb) acc[cb] = (float4v){0.f, 0.f, 0.f, 0.f};

    int rs = tid >> 4, c0 = (tid & 15) * 8;
#pragma unroll
    for (int j = 0; j < 4; ++j) {
        int r = rs + j * 16;
        int n = n0 + r;
        float4 v0 = {}, v1 = {};
        if (n < N) {
            const float* p = h + (size_t)n * H + c0;
            v0 = *(const float4*)p;
            v1 = *(const float4*)(p + 4);
        }
        short8v o;
        o[0] = (short)f2bf(v0.x); o[1] = (short)f2bf(v0.y);
        o[2] = (short)f2bf(v0.z); o[3] = (short)f2bf(v0.w);
        o[4] = (short)f2bf(v1.x); o[5] = (short)f2bf(v1.y);
        o[6] = (short)f2bf(v1.z); o[7] = (short)f2bf(v1.w);
        *(short8v*)((char*)Xs + r * 256 + ((c0 * 2) ^ ((r & 7) << 4))) = o;
    }
    __syncthreads();
    int rloc = wave * 16 + (lane & 15);
    int swz = (rloc & 7) << 4;
#pragma unroll
    for (int ks = 0; ks < 4; ++ks) {
        int boff = rloc * 256 + (((ks * 64) + ((lane >> 4) << 4)) ^ swz);
        short8v a = *(short8v*)((char*)Xs + boff);
        const short* wp = Wf + ((size_t)(ks * 16) * 64 + lane) * 8;
#pragma unroll
        for (int cb = 0; cb < 16; ++cb) {
            short8v b = *(const short8v*)(wp + (size_t)cb * 512);
            acc[cb] = __builtin_amdgcn_mfma_f32_16x16x32_bf16(a, b, acc[cb], 0, 0, 0);
        }
    }
    int col0 = lane & 15;
    int row0 = wave * 16 + ((lane >> 4) << 2);
#pragma unroll
    for (int cb = 0; cb < 16; ++cb) {
        int col = cb * 16 + col0;
        float* dst = (col < 128) ? Y1 : Y2;
        int c = col & 127;
#pragma unroll
        for (int r = 0; r < 4; ++r) {
            int n = n0 + row0 + r;
            if (n < N) dst[(size_t)n * H + c] = acc[cb][r];
        }
    }
}

// ------- aggregation: for each node, reduce relu(Y1[src]+Y2[n]+ef@Wef+pb) -----
// Wef held in 32 VGPRs/thread; ef rows read via the SCALAR pipe (addresses are
// wave-uniform: block-uniform loop counter), so the inner loop is pure v_fmac
// with one SGPR operand. No LDS at all.
__global__ __launch_bounds__(128) void k_edge_agg(
    const float* __restrict__ Y1, const float* __restrict__ Y2,
    const float* __restrict__ ef, const float* __restrict__ Wef,
    const float* __restrict__ pb,
    const int* __restrict__ es_src, const int* __restrict__ es_eid,
    const int* __restrict__ row_start,
    float* __restrict__ s_out, float* __restrict__ mx_out,
    float* __restrict__ mn_out, int N)
{
    int n = blockIdx.x;
    int c = threadIdx.x;   // 0..127 channel
    float wef_r[EDGE_DIM];
#pragma unroll
    for (int k = 0; k < EDGE_DIM; ++k)
        wef_r[k] = Wef[k * H + c];
    int start = row_start[n], end = row_start[n + 1];
    float y2c = Y2[(size_t)n * H + c] + pb[c];
    bool any = end > start;
    float acc_s = 0.f;
    float acc_mx = any ? -3.4e38f : 0.f;
    float acc_mn = any ? 3.4e38f : 0.f;
#pragma unroll 2
    for (int p = start; p < end; ++p) {
        int sn  = __builtin_amdgcn_readfirstlane(es_src[p]);
        int eid = __builtin_amdgcn_readfirstlane(es_eid[p]);
        float acc = Y1[(size_t)sn * H + c] + y2c;
        const float* efp = ef + (size_t)eid * EDGE_DIM;
#pragma unroll
        for (int k = 0; k < EDGE_DIM; ++k)
            acc = fmaf(efp[k], wef_r[k], acc);
        acc = fmaxf(acc, 0.f);
        acc_s += acc;
        acc_mx = fmaxf(acc_mx, acc);
        acc_mn = fminf(acc_mn, acc);
    }
    size_t o = (size_t)n * H + c;
    s_out[o] = acc_s;
    mx_out[o] = acc_mx;
    mn_out[o] = acc_mn;
}

// ---------------- posttrans via MFMA: h += relu(X @ qW + qb) ----------------
// 32 rows/block, 2 waves -> 625 blocks for occupancy.
__global__ __launch_bounds__(128) void k_post_mfma(
    float* __restrict__ h,
    const float* __restrict__ s_in, const float* __restrict__ mx_in,
    const float* __restrict__ mn_in,
    const float* __restrict__ invd, const float* __restrict__ amp,
    const float* __restrict__ att,
    const short* __restrict__ Wf, const float* __restrict__ qb, int N)
{
    __shared__ __align__(16) short Xs[32 * 128];   // 8 KB, XOR-swizzled
    __shared__ float scal[3][32];
    int tid = threadIdx.x;
    int n0 = blockIdx.x * 32;
    int lane = tid & 63, wave = tid >> 6;

    if (tid < 96) {
        int which = tid >> 5, r = tid & 31;
        int n = n0 + r;
        const float* sp = (which == 0) ? invd : (which == 1 ? amp : att);
        scal[which][r] = (n < N) ? sp[n] : 0.f;
    }

    float4v acc[8];
#pragma unroll
    for (int cb = 0; cb < 8; ++cb) acc[cb] = (float4v){0.f, 0.f, 0.f, 0.f};

    int rs = tid >> 4;           // staging row base 0..7
    int c0 = (tid & 15) * 8;     // staging col base (floats)

    for (int kb = 0; kb < 13; ++kb) {
        const float* srcp;
        int comp = 0, grp = 0;
        if (kb == 0) {
            srcp = h;
        } else {
            comp = (kb - 1) & 3;          // 0 mean, 1 max, 2 min, 3 sum
            grp  = (kb - 1) >> 2;         // 0: x1, 1: x amp, 2: x att
            srcp = (comp == 1) ? mx_in : (comp == 2 ? mn_in : s_in);
        }
#pragma unroll
        for (int j = 0; j < 4; ++j) {
            int r = rs + j * 8;
            int n = n0 + r;
            float4 v0 = {}, v1 = {};
            if (n < N) {
                const float* p = srcp + (size_t)n * H + c0;
                v0 = *(const float4*)p;
                v1 = *(const float4*)(p + 4);
            }
            float f = 1.f;
            if (kb != 0) {
                f = (grp == 0) ? 1.f : scal[grp][r];
                if (comp == 0) f *= scal[0][r];
            }
            short8v o;
            o[0] = (short)f2bf(v0.x * f); o[1] = (short)f2bf(v0.y * f);
            o[2] = (short)f2bf(v0.z * f); o[3] = (short)f2bf(v0.w * f);
            o[4] = (short)f2bf(v1.x * f); o[5] = (short)f2bf(v1.y * f);
            o[6] = (short)f2bf(v1.z * f); o[7] = (short)f2bf(v1.w * f);
            *(short8v*)((char*)Xs + r * 256 + ((c0 * 2) ^ ((r & 7) << 4))) = o;
        }
        __syncthreads();
        int rloc = wave * 16 + (lane & 15);   // 0..31
        int swz = (rloc & 7) << 4;
#pragma unroll
        for (int ks = 0; ks < 4; ++ks) {
            int boff = rloc * 256 + (((ks * 64) + ((lane >> 4) << 4)) ^ swz);
            short8v a = *(short8v*)((char*)Xs + boff);
            const short* wp = Wf + ((size_t)((kb * 4 + ks) * 8) * 64 + lane) * 8;
#pragma unroll
            for (int cb = 0; cb < 8; ++cb) {
                short8v b = *(const short8v*)(wp + (size_t)cb * 512);
                acc[cb] = __builtin_amdgcn_mfma_f32_16x16x32_bf16(a, b, acc[cb], 0, 0, 0);
            }
        }
        __syncthreads();
    }
    int col0 = lane & 15;
    int row0 = wave * 16 + ((lane >> 4) << 2);  // 0..31
#pragma unroll
    for (int cb = 0; cb < 8; ++cb) {
        int col = cb * 16 + col0;
        float bb = qb[col];
#pragma unroll
        for (int r = 0; r < 4; ++r) {
            int n = n0 + row0 + r;
            if (n < N)
                h[(size_t)n * H + col] += fmaxf(acc[cb][r] + bb, 0.f);
        }
    }
}

// ---------------- graph readout scatter ----------------
__global__ void k_readout_scatter(const float* __restrict__ h, const int* __restrict__ n2g,
                                  float* __restrict__ g_sum, unsigned int* __restrict__ g_max,
                                  int N) {
    int gid = blockIdx.x * blockDim.x + threadIdx.x;
    int n = gid >> 7, c = gid & 127;
    if (n >= N) return;
    int g = n2g[n];
    float v = h[(size_t)n * H + c];
    atomicAdd(&g_sum[(size_t)g * H + c], v);
    atomicMax(&g_max[(size_t)g * H + c], __float_as_uint(v));  // h >= 0 always
}

__global__ void k_gcnt(const int* __restrict__ n2g, float* __restrict__ g_cnt, int N) {
    int n = blockIdx.x * blockDim.x + threadIdx.x;
    if (n < N) atomicAdd(&g_cnt[n2g[n]], 1.f);
}

// ---------------- final MLP ----------------
__global__ __launch_bounds__(256) void k_final(
    const float* __restrict__ g_sum, const float* __restrict__ g_max,
    const float* __restrict__ g_cnt,
    const float* __restrict__ W1, const float* __restrict__ b1,
    const float* __restrict__ W2, const float* __restrict__ b2,
    float* __restrict__ out)
{
    __shared__ float hid[H];
    int b = blockIdx.x, t = threadIdx.x;
    float cnt = g_cnt[b];
    if (t < H) {
        float acc = 0.f;
        float rc = 1.f / fmaxf(cnt, 1.f);
        for (int k = 0; k < 3 * H; ++k) {
            float x;
            if (k < H)          x = g_sum[(size_t)b * H + k] * rc;
            else if (k < 2 * H) x = (cnt > 0.f) ? g_max[(size_t)b * H + (k - H)] : 0.f;
            else                x = g_sum[(size_t)b * H + (k - 2 * H)];
            acc += x * W1[k * H + t];
        }
        hid[t] = fmaxf(acc + b1[t], 0.f);
    }
    __syncthreads();
    float acc = 0.f;
#pragma unroll 8
    for (int k = 0; k < H; ++k)
        acc += hid[k] * W2[k * T_OUT + t];
    out[(size_t)b * T_OUT + t] = acc + b2[t];
}

extern "C" void kernel_launch(void* const* d_in, const int* in_sizes, int n_in,
                              void* d_out, int out_size, void* d_ws, size_t ws_size,
                              hipStream_t stream) {
    const float* node_feat = (const float*)d_in[0];
    const float* edge_feat = (const float*)d_in[1];
    const float* W_in  = (const float*)d_in[2];
    const float* b_in  = (const float*)d_in[3];
    const float* pre_W = (const float*)d_in[4];
    const float* pre_b = (const float*)d_in[5];
    const float* post_W = (const float*)d_in[6];
    const float* post_b = (const float*)d_in[7];
    const float* out_W1 = (const float*)d_in[8];
    const float* out_b1 = (const float*)d_in[9];
    const float* out_W2 = (const float*)d_in[10];
    const float* out_b2 = (const float*)d_in[11];
    const int* src = (const int*)d_in[12];
    const int* dst = (const int*)d_in[13];
    const int* n2g = (const int*)d_in[14];

    int N = in_sizes[0] / NODE_DIM;
    int E = in_sizes[1] / EDGE_DIM;
    int B = out_size / T_OUT;
    float* out = (float*)d_out;

    float* ws = (float*)d_ws;
    float* h      = ws; ws += (size_t)N * H;
    float* s_buf  = ws; ws += (size_t)N * H;
    float* mx     = ws; ws += (size_t)N * H;
    float* mn     = ws; ws += (size_t)N * H;
    float* Y1     = ws; ws += (size_t)N * H;
    float* Y2     = ws; ws += (size_t)N * H;
    float* invd = ws; ws += N;
    float* amp  = ws; ws += N;
    float* att  = ws; ws += N;
    float* g_sum = ws; ws += (size_t)B * H;
    unsigned int* g_max = (unsigned int*)ws; ws += (size_t)B * H;
    float* g_cnt = ws; ws += B;
    int* deg_i     = (int*)ws; ws += N;
    int* row_start = (int*)ws; ws += N + 1;
    int* cursor    = (int*)ws; ws += N;
    int* es_src    = (int*)ws; ws += E;
    int* es_eid    = (int*)ws; ws += E;
    short* wf_post_all = (short*)ws; ws += (size_t)L_DEPTH * POST_FRAGS * 8 / 2;
    short* wf_y_all    = (short*)ws; ws += (size_t)L_DEPTH * Y_FRAGS * 8 / 2;

    // input MLP
    k_input_mlp<<<((size_t)N * H + 255) / 256, 256, 0, stream>>>(node_feat, W_in, b_in, h, N);

    // edge sort by dst (dst static across layers)
    hipMemsetAsync(deg_i, 0, (size_t)N * sizeof(int), stream);
    k_hist<<<(E + 255) / 256, 256, 0, stream>>>(dst, deg_i, E);
    k_scan<<<1, 1024, 0, stream>>>(deg_i, row_start, cursor, N);
    k_sortscatter<<<(E + 255) / 256, 256, 0, stream>>>(src, dst, cursor, es_src, es_eid, E);
    k_scalers<<<(N + 255) / 256, 256, 0, stream>>>(deg_i, invd, amp, att, N);

    // all-layer weight conversion (once)
    {
        int tot = L_DEPTH * (POST_FRAGS + Y_FRAGS);
        k_wconv_all<<<(tot + 255) / 256, 256, 0, stream>>>(pre_W, post_W, wf_y_all, wf_post_all);
    }

    for (int l = 0; l < L_DEPTH; ++l) {
        const float* pW = pre_W + (size_t)l * KPRE * H;
        k_ygemm_mfma<<<(N + 63) / 64, 256, 0, stream>>>(
            h, wf_y_all + (size_t)l * Y_FRAGS * 8, Y1, Y2, N);
        k_edge_agg<<<N, 128, 0, stream>>>(
            Y1, Y2, edge_feat, pW + (size_t)2 * H * H, pre_b + (size_t)l * H,
            es_src, es_eid, row_start, s_buf, mx, mn, N);
        k_post_mfma<<<(N + 31) / 32, 128, 0, stream>>>(
            h, s_buf, mx, mn, invd, amp, att,
            wf_post_all + (size_t)l * POST_FRAGS * 8, post_b + (size_t)l * H, N);
    }

    // readout
    hipMemsetAsync(g_sum, 0, (size_t)B * H * sizeof(float), stream);
    hipMemsetAsync(g_max, 0, (size_t)B * H * sizeof(float), stream);
    hipMemsetAsync(g_cnt, 0, (size_t)B * sizeof(float), stream);
    k_readout_scatter<<<((size_t)N * H + 255) / 256, 256, 0, stream>>>(h, n2g, g_sum, g_max, N);
    k_gcnt<<<(N + 255) / 256, 256, 0, stream>>>(n2g, g_cnt, N);
    k_final<<<B, 256, 0, stream>>>(g_sum, (const float*)g_max, g_cnt,
                                   out_W1, out_b1, out_W2, out_b2, out);
}